// Round 2
// baseline (361.038 us; speedup 1.0000x reference)
//
#include <hip/hip_runtime.h>
#include <hip/hip_bf16.h>
#include <stdint.h>

typedef __attribute__((ext_vector_type(4))) float          f32x4;
typedef __attribute__((ext_vector_type(8))) short          short8;
typedef __attribute__((ext_vector_type(4))) unsigned short u16x4;

#define F            20480
#define NROWS        4096
#define NPAD         144
#define BK           64
#define CHUNK_BYTES  (NPAD * BK * 2)   /* 18432 bytes per staged B K-chunk */
#define TOTAL_CHUNKS (F / BK)          /* 320 */
#define MB           128               /* GEMM rows per block */

static __device__ __forceinline__ unsigned short f2bf(float f) {
    unsigned u = __builtin_bit_cast(unsigned, f);
    unsigned r = (u + 0x7FFFu + ((u >> 16) & 1u)) >> 16;   // round-to-nearest-even
    return (unsigned short)r;
}

// ---------------------------------------------------------------------------
// Prep: weights f32 -> bf16, laid out per K-chunk in the *inverse-swizzled*
// order so that linear global_load_lds staging yields an LDS image where
//   lds_byte(n, k) = n*128 + ((k*2) ^ ((n&7)<<4))
// (bank-conflict-free for the fragment ds_read_b128 pattern).
// Rows: n<128 -> w_acc[n], n==128/129 -> w_psqt[0/1], n>=130 -> 0 (pad).
// ---------------------------------------------------------------------------
__global__ __launch_bounds__(256) void prep_b(const float* __restrict__ w_acc,
                                              const float* __restrict__ w_psqt,
                                              unsigned short* __restrict__ Bp) {
    int gid = blockIdx.x * 256 + threadIdx.x;      // 737280 threads, 8 B each
    int p8    = gid * 8;                           // output byte offset
    int chunk = p8 / CHUNK_BYTES;
    int win   = p8 % CHUNK_BYTES;
    int n     = win >> 7;                          // row within chunk (0..143)
    int sb    = win & 127;                         // byte within row (8-aligned)
    int kbyte = sb ^ ((n & 7) << 4);               // inverse swizzle
    int k0    = chunk * 64 + (kbyte >> 1);         // 4-aligned -> float4 OK
    f32x4 v = {0.f, 0.f, 0.f, 0.f};
    if (n < 128)      v = *(const f32x4*)(w_acc  + (size_t)n * F + k0);
    else if (n < 130) v = *(const f32x4*)(w_psqt + (size_t)(n - 128) * F + k0);
    u16x4 pk;
    pk[0] = f2bf(v[0]); pk[1] = f2bf(v[1]); pk[2] = f2bf(v[2]); pk[3] = f2bf(v[3]);
    *(u16x4*)((char*)Bp + p8) = pk;
}

// ---------------------------------------------------------------------------
// Main GEMM: grid (64 row-groups, KS k-slices), 256 thr = 4 waves.
// KS=16 -> 1024 blocks = 4 blocks/CU (LDS-limited: 4 x 36KB = 144/160 KB),
// 16 waves/CU for latency hiding across the per-iter vmcnt(0) barrier drain.
// Wave w owns GEMM rows [w*32, w*32+32) of its block's 128 rows.
// A (f32) loaded directly to regs in fragment layout + cvt to bf16.
// B staged bf16 via global_load_lds into double-buffered LDS.
// acc[2][9] 16x16 tiles -> partial[ks][row][144] f32.
// ---------------------------------------------------------------------------
__global__ __launch_bounds__(256, 4) void gemm_main(
    const float* __restrict__ white, const float* __restrict__ black,
    const unsigned short* __restrict__ Bp, float* __restrict__ partial,
    int chunks_per_ks)
{
    __shared__ alignas(16) unsigned short Blds[2][CHUNK_BYTES / 2];

    const int tid  = threadIdx.x;
    const int wave = tid >> 6;
    const int lane = tid & 63;
    const int g    = lane >> 4;      // k-group 0..3
    const int r16  = lane & 15;      // row/col within 16-tile

    const int rg   = blockIdx.x;     // 0..63
    const int row0 = rg * MB;        // GEMM row (0..8191)
    const float* Aside = (row0 < NROWS) ? white : black;
    const int arow0 = row0 & (NROWS - 1);

    const int chunk0 = blockIdx.y * chunks_per_ks;
    const int nch    = chunks_per_ks;

    // A fragment row pointers (mt=0,1), g*8 k-offset folded in
    const float* aRow0 = Aside + (size_t)(arow0 + wave * 32 + r16) * F + g * 8;
    const float* aRow1 = aRow0 + (size_t)16 * F;

    f32x4 apf[2][2][2];   // [mt][kk][lo/hi] prefetched A f32
    f32x4 acc[2][9];
    const f32x4 zero = {0.f, 0.f, 0.f, 0.f};
    #pragma unroll
    for (int m = 0; m < 2; ++m)
        #pragma unroll
        for (int n = 0; n < 9; ++n) acc[m][n] = zero;

    auto stageB = [&](int buf, int chunk) {
        const char* src = (const char*)Bp + (size_t)chunk * CHUNK_BYTES + lane * 16;
        char* dst = (char*)(&Blds[buf][0]);
        #pragma unroll
        for (int line = 0; line < 5; ++line) {
            int li = wave + line * 4;            // waves split the 18 lines
            if (li < 18)
                __builtin_amdgcn_global_load_lds(
                    (const __attribute__((address_space(1))) void*)(src + li * 1024),
                    (__attribute__((address_space(3))) void*)(dst + li * 1024),
                    16, 0, 0);
        }
    };

    auto loadA = [&](int kbase) {
        const float* p0 = aRow0 + kbase;
        const float* p1 = aRow1 + kbase;
        apf[0][0][0] = *(const f32x4*)(p0);
        apf[0][0][1] = *(const f32x4*)(p0 + 4);
        apf[0][1][0] = *(const f32x4*)(p0 + 32);
        apf[0][1][1] = *(const f32x4*)(p0 + 36);
        apf[1][0][0] = *(const f32x4*)(p1);
        apf[1][0][1] = *(const f32x4*)(p1 + 4);
        apf[1][1][0] = *(const f32x4*)(p1 + 32);
        apf[1][1][1] = *(const f32x4*)(p1 + 36);
    };

    stageB(0, chunk0);
    loadA(chunk0 * BK);

    for (int t = 0; t < nch; ++t) {
        __syncthreads();   // compiler drains vmcnt before barrier -> B(t) + A(t) ready

        // convert this iter's A to bf16 fragments (k = kk*32 + g*8 + j, consecutive)
        short8 afr[2][2];
        #pragma unroll
        for (int m = 0; m < 2; ++m)
            #pragma unroll
            for (int kk = 0; kk < 2; ++kk) {
                short8 r;
                #pragma unroll
                for (int j = 0; j < 4; ++j) {
                    r[j]     = (short)f2bf(apf[m][kk][0][j]);
                    r[j + 4] = (short)f2bf(apf[m][kk][1][j]);
                }
                afr[m][kk] = r;
            }

        if (t + 1 < nch) {            // prefetch next iter (issued early, waited at next barrier)
            stageB((t + 1) & 1, chunk0 + t + 1);
            loadA((chunk0 + t + 1) * BK);
        }

        const char* bb = (const char*)(&Blds[t & 1][0]);
        #pragma unroll
        for (int kk = 0; kk < 2; ++kk) {
            #pragma unroll
            for (int n = 0; n < 9; ++n) {
                const int nn  = n * 16 + r16;
                const int off = nn * 128 + ((kk * 64 + g * 16) ^ ((nn & 7) << 4));
                short8 bf = *(const short8*)(bb + off);   // ds_read_b128, swizzled
                acc[0][n] = __builtin_amdgcn_mfma_f32_16x16x32_bf16(afr[0][kk], bf, acc[0][n], 0, 0, 0);
                acc[1][n] = __builtin_amdgcn_mfma_f32_16x16x32_bf16(afr[1][kk], bf, acc[1][n], 0, 0, 0);
            }
        }
    }

    // C-write: C/D layout col = lane&15, row = (lane>>4)*4 + j  [m89-verified]
    float* prow = partial + ((size_t)blockIdx.y * 8192 + row0 + wave * 32 + g * 4) * NPAD;
    #pragma unroll
    for (int m = 0; m < 2; ++m)
        #pragma unroll
        for (int n = 0; n < 9; ++n)
            #pragma unroll
            for (int j = 0; j < 4; ++j)
                prow[(m * 16 + j) * NPAD + n * 16 + r16] = acc[m][n][j];
}

// ---------------------------------------------------------------------------
// Epilogue: reduce split-K partials, bias+clip, 128->2 layer, psqt combine.
// One wave per batch row; lane covers acc indices {lane, lane+64}.
// ---------------------------------------------------------------------------
__global__ __launch_bounds__(256) void epilogue(
    const float* __restrict__ partial, const float* __restrict__ b_acc,
    const float* __restrict__ w_layer, float* __restrict__ out, int KS)
{
    const int wave = threadIdx.x >> 6, lane = threadIdx.x & 63;
    const int b = blockIdx.x * 4 + wave;     // 0..4095
    float sw0 = 0, sw1 = 0, sb0 = 0, sb1 = 0, q0 = 0, q1 = 0;
    for (int ks = 0; ks < KS; ++ks) {
        const float* Pw = partial + ((size_t)ks * 8192 + b) * NPAD;
        const float* Pb = partial + ((size_t)ks * 8192 + NROWS + b) * NPAD;
        sw0 += Pw[lane];      sw1 += Pw[lane + 64];
        sb0 += Pb[lane];      sb1 += Pb[lane + 64];
        q0  += Pw[128] - Pb[128];
        q1  += Pw[129] - Pb[129];
    }
    float wa0 = fminf(fmaxf(sw0 + b_acc[lane], 0.f), 1.f);
    float wa1 = fminf(fmaxf(sw1 + b_acc[lane + 64], 0.f), 1.f);
    float ba0 = fminf(fmaxf(sb0 + b_acc[lane], 0.f), 1.f);
    float ba1 = fminf(fmaxf(sb1 + b_acc[lane + 64], 0.f), 1.f);
    float d0 = wa0 - ba0, d1 = wa1 - ba1;
    float p0 = w_layer[lane] * d0       + w_layer[lane + 64] * d1;
    float p1 = w_layer[128 + lane] * d0 + w_layer[192 + lane] * d1;
    #pragma unroll
    for (int off = 32; off >= 1; off >>= 1) {
        p0 += __shfl_xor(p0, off, 64);
        p1 += __shfl_xor(p1, off, 64);
    }
    if (lane == 0) {
        out[b * 2 + 0] = q0 + p0;
        out[b * 2 + 1] = q1 + p1;
    }
}

// ---------------------------------------------------------------------------
extern "C" void kernel_launch(void* const* d_in, const int* in_sizes, int n_in,
                              void* d_out, int out_size, void* d_ws, size_t ws_size,
                              hipStream_t stream)
{
    const float* white   = (const float*)d_in[0];
    const float* black   = (const float*)d_in[1];
    const float* w_psqt  = (const float*)d_in[2];
    const float* w_acc   = (const float*)d_in[3];
    const float* b_acc   = (const float*)d_in[4];
    const float* w_layer = (const float*)d_in[5];
    float* out = (float*)d_out;

    const size_t bbytes = (size_t)TOTAL_CHUNKS * CHUNK_BYTES;  // 5,898,240
    unsigned short* Bp = (unsigned short*)d_ws;
    float* partial = (float*)((char*)d_ws + bbytes);

    const size_t per_ks = (size_t)8192 * NPAD * 4;             // 4.72 MB
    int KS = 1;
    const int cands[6] = {16, 8, 5, 4, 2, 1};
    for (int i = 0; i < 6; ++i)
        if (bbytes + (size_t)cands[i] * per_ks <= ws_size) { KS = cands[i]; break; }
    int chunks_per_ks = TOTAL_CHUNKS / KS;

    prep_b   <<<dim3(2880),     dim3(256), 0, stream>>>(w_acc, w_psqt, Bp);
    gemm_main<<<dim3(64, KS),   dim3(256), 0, stream>>>(white, black, Bp, partial, chunks_per_ks);
    epilogue <<<dim3(1024),     dim3(256), 0, stream>>>(partial, b_acc, w_layer, out, KS);
}

// Round 3
// 273.333 us; speedup vs baseline: 1.3209x; 1.3209x over previous
//
#include <hip/hip_runtime.h>
#include <hip/hip_bf16.h>
#include <stdint.h>

typedef __attribute__((ext_vector_type(4))) float          f32x4;
typedef __attribute__((ext_vector_type(8))) short          short8;
typedef __attribute__((ext_vector_type(4))) unsigned short u16x4;

#define F            20480
#define NROWS        4096
#define NPAD         144
#define BK           64
#define CHUNK_BYTES  (NPAD * BK * 2)   /* 18432 bytes per B K-chunk */
#define TOTAL_CHUNKS (F / BK)          /* 320 */

static __device__ __forceinline__ unsigned short f2bf(float f) {
    unsigned u = __builtin_bit_cast(unsigned, f);
    unsigned r = (u + 0x7FFFu + ((u >> 16) & 1u)) >> 16;   // round-to-nearest-even
    return (unsigned short)r;
}

// ---------------------------------------------------------------------------
// Prep: weights f32 -> bf16, per-chunk row-major [144 rows][64 k] (128 B/row).
// No swizzle needed — B is consumed straight from L2/L3 by the GEMM.
// Rows: n<128 -> w_acc[n], n==128/129 -> w_psqt[0/1], n>=130 -> 0 (pad).
// ---------------------------------------------------------------------------
__global__ __launch_bounds__(256) void prep_b(const float* __restrict__ w_acc,
                                              const float* __restrict__ w_psqt,
                                              unsigned short* __restrict__ Bp) {
    int gid = blockIdx.x * 256 + threadIdx.x;      // 737280 threads, 8 B each
    int p8    = gid * 8;                           // output byte offset
    int chunk = p8 / CHUNK_BYTES;
    int win   = p8 % CHUNK_BYTES;
    int n     = win >> 7;                          // row within chunk (0..143)
    int sb    = win & 127;                         // byte within row (8-aligned)
    int k0    = chunk * 64 + (sb >> 1);
    f32x4 v = {0.f, 0.f, 0.f, 0.f};
    if (n < 128)      v = *(const f32x4*)(w_acc  + (size_t)n * F + k0);
    else if (n < 130) v = *(const f32x4*)(w_psqt + (size_t)(n - 128) * F + k0);
    u16x4 pk;
    pk[0] = f2bf(v[0]); pk[1] = f2bf(v[1]); pk[2] = f2bf(v[2]); pk[3] = f2bf(v[3]);
    *(u16x4*)((char*)Bp + p8) = pk;
}

// ---------------------------------------------------------------------------
// Barrier-free GEMM. Each WAVE is fully independent: 32 GEMM rows x 144 cols
// over a K-slice of chunks. No LDS, no __syncthreads -> no vmcnt(0) drains.
// A (f32, HBM) prefetched one chunk ahead into regs; B (bf16, 5.9 MB total,
// L2/L3-resident) fragments loaded directly from global each iteration.
// 2048 waves (KS=8) = 8 waves/CU; ~210 unified regs -> 2 waves/SIMD, no spill.
// ---------------------------------------------------------------------------
__global__ __launch_bounds__(256, 2) void gemm_main(
    const float* __restrict__ white, const float* __restrict__ black,
    const unsigned short* __restrict__ Bp, float* __restrict__ partial,
    int chunks_per_ks)
{
    const int tid  = threadIdx.x;
    const int wave = tid >> 6;
    const int lane = tid & 63;
    const int g    = lane >> 4;      // k-group 0..3
    const int r16  = lane & 15;      // row/col within 16-tile

    const int wid = blockIdx.x * 4 + wave;   // global wave id
    const int rg  = wid & 255;               // row-group: 32 GEMM rows
    const int ks  = wid >> 8;                // k-slice

    const int grow0 = rg * 32;               // GEMM row 0..8191
    const float* Aside = (grow0 < NROWS) ? white : black;
    const int arow0 = grow0 & (NROWS - 1);

    const int chunk0 = ks * chunks_per_ks;
    const int nch    = chunks_per_ks;

    // A fragment row pointers (m=0,1), g*8 k-offset folded in
    const float* aRow0 = Aside + (size_t)(arow0 + r16) * F + g * 8;
    const float* aRow1 = aRow0 + (size_t)16 * F;
    // B per-lane base: row r16, k-subcol g (16 B)
    const char* bBase = (const char*)Bp + r16 * 128 + g * 16;

    f32x4 apf[2][2][2];   // [m][kk][lo/hi] prefetched A f32
    f32x4 acc[2][9];
    const f32x4 zero = {0.f, 0.f, 0.f, 0.f};
    #pragma unroll
    for (int m = 0; m < 2; ++m)
        #pragma unroll
        for (int n = 0; n < 9; ++n) acc[m][n] = zero;

    auto loadA = [&](int kbase) {
        const float* p0 = aRow0 + kbase;
        const float* p1 = aRow1 + kbase;
        apf[0][0][0] = *(const f32x4*)(p0);
        apf[0][0][1] = *(const f32x4*)(p0 + 4);
        apf[0][1][0] = *(const f32x4*)(p0 + 32);
        apf[0][1][1] = *(const f32x4*)(p0 + 36);
        apf[1][0][0] = *(const f32x4*)(p1);
        apf[1][0][1] = *(const f32x4*)(p1 + 4);
        apf[1][1][0] = *(const f32x4*)(p1 + 32);
        apf[1][1][1] = *(const f32x4*)(p1 + 36);
    };

    loadA(chunk0 * BK);

    for (int t = 0; t < nch; ++t) {
        // Issue all 18 B-fragment loads for this chunk (L2/L3 hits).
        const char* bc = bBase + (size_t)(chunk0 + t) * CHUNK_BYTES;
        short8 bfr[2][9];
        #pragma unroll
        for (int kk = 0; kk < 2; ++kk)
            #pragma unroll
            for (int n = 0; n < 9; ++n)
                bfr[kk][n] = *(const short8*)(bc + n * 2048 + kk * 64);

        // Convert this iter's A to bf16 fragments (k = kk*32 + g*8 + j)
        short8 afr[2][2];
        #pragma unroll
        for (int m = 0; m < 2; ++m)
            #pragma unroll
            for (int kk = 0; kk < 2; ++kk) {
                short8 r;
                #pragma unroll
                for (int j = 0; j < 4; ++j) {
                    r[j]     = (short)f2bf(apf[m][kk][0][j]);
                    r[j + 4] = (short)f2bf(apf[m][kk][1][j]);
                }
                afr[m][kk] = r;
            }

        // Prefetch next chunk's A (HBM latency hides under MFMAs below)
        if (t + 1 < nch) loadA((chunk0 + t + 1) * BK);

        #pragma unroll
        for (int kk = 0; kk < 2; ++kk)
            #pragma unroll
            for (int n = 0; n < 9; ++n) {
                acc[0][n] = __builtin_amdgcn_mfma_f32_16x16x32_bf16(afr[0][kk], bfr[kk][n], acc[0][n], 0, 0, 0);
                acc[1][n] = __builtin_amdgcn_mfma_f32_16x16x32_bf16(afr[1][kk], bfr[kk][n], acc[1][n], 0, 0, 0);
            }
    }

    // C-write: C/D layout col = lane&15, row = (lane>>4)*4 + j  [m89-verified]
    float* prow = partial + ((size_t)ks * 8192 + grow0 + g * 4) * NPAD;
    #pragma unroll
    for (int m = 0; m < 2; ++m)
        #pragma unroll
        for (int n = 0; n < 9; ++n)
            #pragma unroll
            for (int j = 0; j < 4; ++j)
                prow[(m * 16 + j) * NPAD + n * 16 + r16] = acc[m][n][j];
}

// ---------------------------------------------------------------------------
// Epilogue: reduce split-K partials, bias+clip, 128->2 layer, psqt combine.
// One wave per batch row; lane covers acc indices {lane, lane+64}.
// ---------------------------------------------------------------------------
__global__ __launch_bounds__(256) void epilogue(
    const float* __restrict__ partial, const float* __restrict__ b_acc,
    const float* __restrict__ w_layer, float* __restrict__ out, int KS)
{
    const int wave = threadIdx.x >> 6, lane = threadIdx.x & 63;
    const int b = blockIdx.x * 4 + wave;     // 0..4095
    float sw0 = 0, sw1 = 0, sb0 = 0, sb1 = 0, q0 = 0, q1 = 0;
    for (int ks = 0; ks < KS; ++ks) {
        const float* Pw = partial + ((size_t)ks * 8192 + b) * NPAD;
        const float* Pb = partial + ((size_t)ks * 8192 + NROWS + b) * NPAD;
        sw0 += Pw[lane];      sw1 += Pw[lane + 64];
        sb0 += Pb[lane];      sb1 += Pb[lane + 64];
        q0  += Pw[128] - Pb[128];
        q1  += Pw[129] - Pb[129];
    }
    float wa0 = fminf(fmaxf(sw0 + b_acc[lane], 0.f), 1.f);
    float wa1 = fminf(fmaxf(sw1 + b_acc[lane + 64], 0.f), 1.f);
    float ba0 = fminf(fmaxf(sb0 + b_acc[lane], 0.f), 1.f);
    float ba1 = fminf(fmaxf(sb1 + b_acc[lane + 64], 0.f), 1.f);
    float d0 = wa0 - ba0, d1 = wa1 - ba1;
    float p0 = w_layer[lane] * d0       + w_layer[lane + 64] * d1;
    float p1 = w_layer[128 + lane] * d0 + w_layer[192 + lane] * d1;
    #pragma unroll
    for (int off = 32; off >= 1; off >>= 1) {
        p0 += __shfl_xor(p0, off, 64);
        p1 += __shfl_xor(p1, off, 64);
    }
    if (lane == 0) {
        out[b * 2 + 0] = q0 + p0;
        out[b * 2 + 1] = q1 + p1;
    }
}

// ---------------------------------------------------------------------------
extern "C" void kernel_launch(void* const* d_in, const int* in_sizes, int n_in,
                              void* d_out, int out_size, void* d_ws, size_t ws_size,
                              hipStream_t stream)
{
    const float* white   = (const float*)d_in[0];
    const float* black   = (const float*)d_in[1];
    const float* w_psqt  = (const float*)d_in[2];
    const float* w_acc   = (const float*)d_in[3];
    const float* b_acc   = (const float*)d_in[4];
    const float* w_layer = (const float*)d_in[5];
    float* out = (float*)d_out;

    const size_t bbytes = (size_t)TOTAL_CHUNKS * CHUNK_BYTES;  // 5,898,240
    unsigned short* Bp = (unsigned short*)d_ws;
    float* partial = (float*)((char*)d_ws + bbytes);

    const size_t per_ks = (size_t)8192 * NPAD * 4;             // 4.72 MB
    int KS = 1;
    const int cands[5] = {8, 5, 4, 2, 1};
    for (int i = 0; i < 5; ++i)
        if (bbytes + (size_t)cands[i] * per_ks <= ws_size) { KS = cands[i]; break; }
    int chunks_per_ks = TOTAL_CHUNKS / KS;
    int n_waves = 256 * KS;

    prep_b   <<<dim3(2880),        dim3(256), 0, stream>>>(w_acc, w_psqt, Bp);
    gemm_main<<<dim3(n_waves / 4), dim3(256), 0, stream>>>(white, black, Bp, partial, chunks_per_ks);
    epilogue <<<dim3(1024),        dim3(256), 0, stream>>>(partial, b_acc, w_layer, out, KS);
}

// Round 4
// 162.696 us; speedup vs baseline: 2.2191x; 1.6800x over previous
//
#include <hip/hip_runtime.h>
#include <hip/hip_bf16.h>
#include <stdint.h>

typedef __attribute__((ext_vector_type(4))) float          f32x4;
typedef __attribute__((ext_vector_type(8))) short          short8;
typedef __attribute__((ext_vector_type(4))) unsigned short u16x4;

#define F            20480
#define NROWS        4096
#define NPAD         144
#define BK           64
#define CHUNK_BYTES  (NPAD * BK * 2)   /* 18432 bytes per staged B K-chunk */
#define TOTAL_CHUNKS (F / BK)          /* 320 */
#define MB           256               /* GEMM rows per block (8 waves x 32) */

static __device__ __forceinline__ unsigned short f2bf(float f) {
    unsigned u = __builtin_bit_cast(unsigned, f);
    unsigned r = (u + 0x7FFFu + ((u >> 16) & 1u)) >> 16;   // round-to-nearest-even
    return (unsigned short)r;
}

// ---------------------------------------------------------------------------
// Prep: weights f32 -> bf16, laid out per K-chunk in the *inverse-swizzled*
// order so that linear global_load_lds staging yields an LDS image where
//   lds_byte(n, k) = n*128 + ((k*2) ^ ((n&7)<<4))
// (bank-conflict-free for the fragment ds_read_b128 pattern; R1 measured 0
// SQ_LDS_BANK_CONFLICT). Rows: n<128 -> w_acc[n], 128/129 -> w_psqt, else 0.
// ---------------------------------------------------------------------------
__global__ __launch_bounds__(256) void prep_b(const float* __restrict__ w_acc,
                                              const float* __restrict__ w_psqt,
                                              unsigned short* __restrict__ Bp) {
    int gid = blockIdx.x * 256 + threadIdx.x;      // 737280 threads, 8 B each
    int p8    = gid * 8;                           // output byte offset
    int chunk = p8 / CHUNK_BYTES;
    int win   = p8 % CHUNK_BYTES;
    int n     = win >> 7;                          // row within chunk (0..143)
    int sb    = win & 127;                         // byte within row (8-aligned)
    int kbyte = sb ^ ((n & 7) << 4);               // inverse swizzle
    int k0    = chunk * 64 + (kbyte >> 1);         // 4-aligned -> float4 OK
    f32x4 v = {0.f, 0.f, 0.f, 0.f};
    if (n < 128)      v = *(const f32x4*)(w_acc  + (size_t)n * F + k0);
    else if (n < 130) v = *(const f32x4*)(w_psqt + (size_t)(n - 128) * F + k0);
    u16x4 pk;
    pk[0] = f2bf(v[0]); pk[1] = f2bf(v[1]); pk[2] = f2bf(v[2]); pk[3] = f2bf(v[3]);
    *(u16x4*)((char*)Bp + p8) = pk;
}

// ---------------------------------------------------------------------------
// Main GEMM: grid (32 row-groups, KS=8 k-slices) = 256 blocks = 1/CU.
// 512 threads = 8 waves; wave w owns GEMM rows [w*32, w*32+32) of the block's
// 256 rows -> B LDS chunk shared by 256 rows (B traffic halved vs MB=128).
// A (f32) loaded directly to regs in fragment layout + cvt to bf16.
// B staged bf16 via global_load_lds, double-buffered. Iter time (~6.9k cy,
// traffic-bound) >> load latency, so 1-ahead prefetch fully hides the
// barrier's vmcnt(0) drain. ~180 regs/wave -> 2 waves/SIMD, no spill.
// ---------------------------------------------------------------------------
__global__ __launch_bounds__(512, 2) void gemm_main(
    const float* __restrict__ white, const float* __restrict__ black,
    const unsigned short* __restrict__ Bp, float* __restrict__ partial,
    int chunks_per_ks)
{
    __shared__ alignas(16) unsigned short Blds[2][CHUNK_BYTES / 2];

    const int tid  = threadIdx.x;
    const int wave = tid >> 6;       // 0..7
    const int lane = tid & 63;
    const int g    = lane >> 4;      // k-group 0..3
    const int r16  = lane & 15;      // row/col within 16-tile

    const int rg   = blockIdx.x;     // 0..31
    const int row0 = rg * MB;        // GEMM row (0..8191), whole block same side
    const float* Aside = (row0 < NROWS) ? white : black;
    const int arow0 = row0 & (NROWS - 1);

    const int chunk0 = blockIdx.y * chunks_per_ks;
    const int nch    = chunks_per_ks;

    // A fragment row pointers (m=0,1), g*8 k-offset folded in
    const float* aRow0 = Aside + (size_t)(arow0 + wave * 32 + r16) * F + g * 8;
    const float* aRow1 = aRow0 + (size_t)16 * F;

    f32x4 apf[2][2][2];   // [m][kk][lo/hi] prefetched A f32
    f32x4 acc[2][9];
    const f32x4 zero = {0.f, 0.f, 0.f, 0.f};
    #pragma unroll
    for (int m = 0; m < 2; ++m)
        #pragma unroll
        for (int n = 0; n < 9; ++n) acc[m][n] = zero;

    auto stageB = [&](int buf, int chunk) {
        const char* src = (const char*)Bp + (size_t)chunk * CHUNK_BYTES + lane * 16;
        char* dst = (char*)(&Blds[buf][0]);
        #pragma unroll
        for (int line = 0; line < 3; ++line) {
            int li = wave + line * 8;            // 8 waves split the 18 lines
            if (li < 18)
                __builtin_amdgcn_global_load_lds(
                    (const __attribute__((address_space(1))) void*)(src + li * 1024),
                    (__attribute__((address_space(3))) void*)(dst + li * 1024),
                    16, 0, 0);
        }
    };

    auto loadA = [&](int kbase) {
        const float* p0 = aRow0 + kbase;
        const float* p1 = aRow1 + kbase;
        apf[0][0][0] = *(const f32x4*)(p0);
        apf[0][0][1] = *(const f32x4*)(p0 + 4);
        apf[0][1][0] = *(const f32x4*)(p0 + 32);
        apf[0][1][1] = *(const f32x4*)(p0 + 36);
        apf[1][0][0] = *(const f32x4*)(p1);
        apf[1][0][1] = *(const f32x4*)(p1 + 4);
        apf[1][1][0] = *(const f32x4*)(p1 + 32);
        apf[1][1][1] = *(const f32x4*)(p1 + 36);
    };

    stageB(0, chunk0);
    loadA(chunk0 * BK);

    for (int t = 0; t < nch; ++t) {
        __syncthreads();   // drains vmcnt -> B(t) + A(t) ready (issued ~full iter ago)

        // convert this iter's A to bf16 fragments (k = kk*32 + g*8 + j)
        short8 afr[2][2];
        #pragma unroll
        for (int m = 0; m < 2; ++m)
            #pragma unroll
            for (int kk = 0; kk < 2; ++kk) {
                short8 r;
                #pragma unroll
                for (int j = 0; j < 4; ++j) {
                    r[j]     = (short)f2bf(apf[m][kk][0][j]);
                    r[j + 4] = (short)f2bf(apf[m][kk][1][j]);
                }
                afr[m][kk] = r;
            }

        if (t + 1 < nch) {            // prefetch next iter early in this iter
            stageB((t + 1) & 1, chunk0 + t + 1);
            loadA((chunk0 + t + 1) * BK);
        }

        const char* bb = (const char*)(&Blds[t & 1][0]);
        #pragma unroll
        for (int kk = 0; kk < 2; ++kk) {
            #pragma unroll
            for (int n = 0; n < 9; ++n) {
                const int nn  = n * 16 + r16;
                const int off = nn * 128 + ((kk * 64 + g * 16) ^ ((nn & 7) << 4));
                short8 bf = *(const short8*)(bb + off);   // ds_read_b128, swizzled
                acc[0][n] = __builtin_amdgcn_mfma_f32_16x16x32_bf16(afr[0][kk], bf, acc[0][n], 0, 0, 0);
                acc[1][n] = __builtin_amdgcn_mfma_f32_16x16x32_bf16(afr[1][kk], bf, acc[1][n], 0, 0, 0);
            }
        }
    }

    // C-write: C/D layout col = lane&15, row = (lane>>4)*4 + j  [m89-verified]
    float* prow = partial + ((size_t)blockIdx.y * 8192 + row0 + wave * 32 + g * 4) * NPAD;
    #pragma unroll
    for (int m = 0; m < 2; ++m)
        #pragma unroll
        for (int n = 0; n < 9; ++n)
            #pragma unroll
            for (int j = 0; j < 4; ++j)
                prow[(m * 16 + j) * NPAD + n * 16 + r16] = acc[m][n][j];
}

// ---------------------------------------------------------------------------
// Epilogue: reduce split-K partials, bias+clip, 128->2 layer, psqt combine.
// One wave per batch row; lane covers acc indices {lane, lane+64}.
// ---------------------------------------------------------------------------
__global__ __launch_bounds__(256) void epilogue(
    const float* __restrict__ partial, const float* __restrict__ b_acc,
    const float* __restrict__ w_layer, float* __restrict__ out, int KS)
{
    const int wave = threadIdx.x >> 6, lane = threadIdx.x & 63;
    const int b = blockIdx.x * 4 + wave;     // 0..4095
    float sw0 = 0, sw1 = 0, sb0 = 0, sb1 = 0, q0 = 0, q1 = 0;
    for (int ks = 0; ks < KS; ++ks) {
        const float* Pw = partial + ((size_t)ks * 8192 + b) * NPAD;
        const float* Pb = partial + ((size_t)ks * 8192 + NROWS + b) * NPAD;
        sw0 += Pw[lane];      sw1 += Pw[lane + 64];
        sb0 += Pb[lane];      sb1 += Pb[lane + 64];
        q0  += Pw[128] - Pb[128];
        q1  += Pw[129] - Pb[129];
    }
    float wa0 = fminf(fmaxf(sw0 + b_acc[lane], 0.f), 1.f);
    float wa1 = fminf(fmaxf(sw1 + b_acc[lane + 64], 0.f), 1.f);
    float ba0 = fminf(fmaxf(sb0 + b_acc[lane], 0.f), 1.f);
    float ba1 = fminf(fmaxf(sb1 + b_acc[lane + 64], 0.f), 1.f);
    float d0 = wa0 - ba0, d1 = wa1 - ba1;
    float p0 = w_layer[lane] * d0       + w_layer[lane + 64] * d1;
    float p1 = w_layer[128 + lane] * d0 + w_layer[192 + lane] * d1;
    #pragma unroll
    for (int off = 32; off >= 1; off >>= 1) {
        p0 += __shfl_xor(p0, off, 64);
        p1 += __shfl_xor(p1, off, 64);
    }
    if (lane == 0) {
        out[b * 2 + 0] = q0 + p0;
        out[b * 2 + 1] = q1 + p1;
    }
}

// ---------------------------------------------------------------------------
extern "C" void kernel_launch(void* const* d_in, const int* in_sizes, int n_in,
                              void* d_out, int out_size, void* d_ws, size_t ws_size,
                              hipStream_t stream)
{
    const float* white   = (const float*)d_in[0];
    const float* black   = (const float*)d_in[1];
    const float* w_psqt  = (const float*)d_in[2];
    const float* w_acc   = (const float*)d_in[3];
    const float* b_acc   = (const float*)d_in[4];
    const float* w_layer = (const float*)d_in[5];
    float* out = (float*)d_out;

    const size_t bbytes = (size_t)TOTAL_CHUNKS * CHUNK_BYTES;  // 5,898,240
    unsigned short* Bp = (unsigned short*)d_ws;
    float* partial = (float*)((char*)d_ws + bbytes);

    const size_t per_ks = (size_t)8192 * NPAD * 4;             // 4.72 MB
    int KS = 1;
    const int cands[5] = {8, 5, 4, 2, 1};
    for (int i = 0; i < 5; ++i)
        if (bbytes + (size_t)cands[i] * per_ks <= ws_size) { KS = cands[i]; break; }
    int chunks_per_ks = TOTAL_CHUNKS / KS;

    prep_b   <<<dim3(2880),   dim3(256), 0, stream>>>(w_acc, w_psqt, Bp);
    gemm_main<<<dim3(32, KS), dim3(512), 0, stream>>>(white, black, Bp, partial, chunks_per_ks);
    epilogue <<<dim3(1024),   dim3(256), 0, stream>>>(partial, b_acc, w_layer, out, KS);
}

// Round 5
// 149.101 us; speedup vs baseline: 2.4214x; 1.0912x over previous
//
#include <hip/hip_runtime.h>
#include <hip/hip_bf16.h>
#include <stdint.h>

typedef __attribute__((ext_vector_type(4))) float          f32x4;
typedef __attribute__((ext_vector_type(8))) short          short8;
typedef __attribute__((ext_vector_type(4))) unsigned short u16x4;

#define F            20480
#define NROWS        4096
#define NPAD         144
#define BK           128
#define CHUNK_BYTES  (NPAD * BK * 2)   /* 36864 bytes per staged B K-chunk */
#define TOTAL_CHUNKS (F / BK)          /* 160 */
#define MB           256               /* GEMM rows per block (8 waves x 32) */

static __device__ __forceinline__ unsigned short f2bf(float f) {
    unsigned u = __builtin_bit_cast(unsigned, f);
    unsigned r = (u + 0x7FFFu + ((u >> 16) & 1u)) >> 16;   // round-to-nearest-even
    return (unsigned short)r;
}

// ---------------------------------------------------------------------------
// Prep: weights f32 -> bf16, per K-chunk (128 k) in *inverse-swizzled* order
// so linear global_load_lds staging yields an LDS image where
//   lds_byte(n, k) = n*256 + ((k*2) ^ ((n&7)<<4))
// (2-way-max bank aliasing on the fragment ds_read_b128 pattern = free; R1/R4
// measured 0 SQ_LDS_BANK_CONFLICT with the same XOR algebra).
// Rows: n<128 -> w_acc[n], n==128/129 -> w_psqt[0/1], n>=130 -> 0 (pad).
// ---------------------------------------------------------------------------
__global__ __launch_bounds__(256) void prep_b(const float* __restrict__ w_acc,
                                              const float* __restrict__ w_psqt,
                                              unsigned short* __restrict__ Bp) {
    int gid = blockIdx.x * 256 + threadIdx.x;      // 737280 threads, 8 B each
    int p8    = gid * 8;                           // output byte offset
    int chunk = p8 / CHUNK_BYTES;
    int win   = p8 % CHUNK_BYTES;
    int n     = win >> 8;                          // row within chunk (0..143)
    int sb    = win & 255;                         // byte within row (8-aligned)
    int kbyte = sb ^ ((n & 7) << 4);               // inverse swizzle (8-align kept)
    int k0    = chunk * BK + (kbyte >> 1);         // multiple of 4 -> f32x4 OK
    f32x4 v = {0.f, 0.f, 0.f, 0.f};
    if (n < 128)      v = *(const f32x4*)(w_acc  + (size_t)n * F + k0);
    else if (n < 130) v = *(const f32x4*)(w_psqt + (size_t)(n - 128) * F + k0);
    u16x4 pk;
    pk[0] = f2bf(v[0]); pk[1] = f2bf(v[1]); pk[2] = f2bf(v[2]); pk[3] = f2bf(v[3]);
    *(u16x4*)((char*)Bp + p8) = pk;
}

// ---------------------------------------------------------------------------
// Main GEMM: grid (32 row-groups, KS=8 k-slices) = 256 blocks = 1/CU.
// 512 threads = 8 waves; wave w owns GEMM rows [w*32, w*32+32) of the block's
// 256 rows. BK=128: 20 iters/slice -> half the barrier/vmcnt(0) drains of R4,
// double the prefetch slack per drain. A (f32) direct to regs + cvt bf16;
// B staged bf16 via global_load_lds, double-buffered (73.7 KB LDS).
// Partials stored f16 (|partial| <~ 1.5, ulp 2.4e-4 -> error ~1e-3 vs 0.052
// threshold). ~200 unified regs/wave -> 2 waves/SIMD, no spill.
// ---------------------------------------------------------------------------
__global__ __launch_bounds__(512, 2) void gemm_main(
    const float* __restrict__ white, const float* __restrict__ black,
    const unsigned short* __restrict__ Bp, _Float16* __restrict__ partial,
    int chunks_per_ks)
{
    __shared__ alignas(16) unsigned short Blds[2][CHUNK_BYTES / 2];

    const int tid  = threadIdx.x;
    const int wave = tid >> 6;       // 0..7
    const int lane = tid & 63;
    const int g    = lane >> 4;      // k-group 0..3
    const int r16  = lane & 15;      // row/col within 16-tile

    const int rg   = blockIdx.x;     // 0..31
    const int row0 = rg * MB;        // GEMM row (0..8191), whole block same side
    const float* Aside = (row0 < NROWS) ? white : black;
    const int arow0 = row0 & (NROWS - 1);

    const int chunk0 = blockIdx.y * chunks_per_ks;
    const int nch    = chunks_per_ks;

    // A fragment row pointers (m=0,1), g*8 k-offset folded in
    const float* aRow0 = Aside + (size_t)(arow0 + wave * 32 + r16) * F + g * 8;
    const float* aRow1 = aRow0 + (size_t)16 * F;

    f32x4 apf[2][4][2];   // [m][kk][lo/hi] prefetched A f32 (BK=128 -> kk 0..3)
    f32x4 acc[2][9];
    const f32x4 zero = {0.f, 0.f, 0.f, 0.f};
    #pragma unroll
    for (int m = 0; m < 2; ++m)
        #pragma unroll
        for (int n = 0; n < 9; ++n) acc[m][n] = zero;

    auto stageB = [&](int buf, int chunk) {
        const char* src = (const char*)Bp + (size_t)chunk * CHUNK_BYTES + lane * 16;
        char* dst = (char*)(&Blds[buf][0]);
        #pragma unroll
        for (int line = 0; line < 5; ++line) {
            int li = wave + line * 8;            // 8 waves split the 36 KB
            if (li < 36)
                __builtin_amdgcn_global_load_lds(
                    (const __attribute__((address_space(1))) void*)(src + li * 1024),
                    (__attribute__((address_space(3))) void*)(dst + li * 1024),
                    16, 0, 0);
        }
    };

    auto loadA = [&](int kbase) {
        #pragma unroll
        for (int m = 0; m < 2; ++m) {
            const float* p = (m ? aRow1 : aRow0) + kbase;
            #pragma unroll
            for (int kk = 0; kk < 4; ++kk) {
                apf[m][kk][0] = *(const f32x4*)(p + kk * 32);
                apf[m][kk][1] = *(const f32x4*)(p + kk * 32 + 4);
            }
        }
    };

    stageB(0, chunk0);
    loadA(chunk0 * BK);

    for (int t = 0; t < nch; ++t) {
        __syncthreads();   // drains vmcnt -> B(t) + A(t) ready (issued ~full iter ago)

        // convert this iter's A to bf16 fragments (k = kk*32 + g*8 + j)
        short8 afr[2][4];
        #pragma unroll
        for (int m = 0; m < 2; ++m)
            #pragma unroll
            for (int kk = 0; kk < 4; ++kk) {
                short8 r;
                #pragma unroll
                for (int j = 0; j < 4; ++j) {
                    r[j]     = (short)f2bf(apf[m][kk][0][j]);
                    r[j + 4] = (short)f2bf(apf[m][kk][1][j]);
                }
                afr[m][kk] = r;
            }

        if (t + 1 < nch) {            // prefetch next iter early in this iter
            stageB((t + 1) & 1, chunk0 + t + 1);
            loadA((chunk0 + t + 1) * BK);
        }

        const char* bb = (const char*)(&Blds[t & 1][0]);
        #pragma unroll
        for (int kk = 0; kk < 4; ++kk) {
            #pragma unroll
            for (int n = 0; n < 9; ++n) {
                const int nn  = n * 16 + r16;
                const int off = nn * 256 + ((kk * 64 + g * 16) ^ ((nn & 7) << 4));
                short8 bf = *(const short8*)(bb + off);   // ds_read_b128, swizzled
                acc[0][n] = __builtin_amdgcn_mfma_f32_16x16x32_bf16(afr[0][kk], bf, acc[0][n], 0, 0, 0);
                acc[1][n] = __builtin_amdgcn_mfma_f32_16x16x32_bf16(afr[1][kk], bf, acc[1][n], 0, 0, 0);
            }
        }
    }

    // C-write (f16): C/D layout col = lane&15, row = (lane>>4)*4 + j
    _Float16* prow = partial + ((size_t)blockIdx.y * 8192 + row0 + wave * 32 + g * 4) * NPAD;
    #pragma unroll
    for (int m = 0; m < 2; ++m)
        #pragma unroll
        for (int n = 0; n < 9; ++n)
            #pragma unroll
            for (int j = 0; j < 4; ++j)
                prow[(m * 16 + j) * NPAD + n * 16 + r16] = (_Float16)acc[m][n][j];
}

// ---------------------------------------------------------------------------
// Epilogue: reduce split-K f16 partials, bias+clip, 128->2 layer, psqt.
// One wave per batch row; lane covers acc indices {lane, lane+64}.
// ---------------------------------------------------------------------------
__global__ __launch_bounds__(256) void epilogue(
    const _Float16* __restrict__ partial, const float* __restrict__ b_acc,
    const float* __restrict__ w_layer, float* __restrict__ out, int KS)
{
    const int wave = threadIdx.x >> 6, lane = threadIdx.x & 63;
    const int b = blockIdx.x * 4 + wave;     // 0..4095
    float sw0 = 0, sw1 = 0, sb0 = 0, sb1 = 0, q0 = 0, q1 = 0;
    for (int ks = 0; ks < KS; ++ks) {
        const _Float16* Pw = partial + ((size_t)ks * 8192 + b) * NPAD;
        const _Float16* Pb = partial + ((size_t)ks * 8192 + NROWS + b) * NPAD;
        sw0 += (float)Pw[lane];      sw1 += (float)Pw[lane + 64];
        sb0 += (float)Pb[lane];      sb1 += (float)Pb[lane + 64];
        q0  += (float)Pw[128] - (float)Pb[128];
        q1  += (float)Pw[129] - (float)Pb[129];
    }
    float wa0 = fminf(fmaxf(sw0 + b_acc[lane], 0.f), 1.f);
    float wa1 = fminf(fmaxf(sw1 + b_acc[lane + 64], 0.f), 1.f);
    float ba0 = fminf(fmaxf(sb0 + b_acc[lane], 0.f), 1.f);
    float ba1 = fminf(fmaxf(sb1 + b_acc[lane + 64], 0.f), 1.f);
    float d0 = wa0 - ba0, d1 = wa1 - ba1;
    float p0 = w_layer[lane] * d0       + w_layer[lane + 64] * d1;
    float p1 = w_layer[128 + lane] * d0 + w_layer[192 + lane] * d1;
    #pragma unroll
    for (int off = 32; off >= 1; off >>= 1) {
        p0 += __shfl_xor(p0, off, 64);
        p1 += __shfl_xor(p1, off, 64);
    }
    if (lane == 0) {
        out[b * 2 + 0] = q0 + p0;
        out[b * 2 + 1] = q1 + p1;
    }
}

// ---------------------------------------------------------------------------
extern "C" void kernel_launch(void* const* d_in, const int* in_sizes, int n_in,
                              void* d_out, int out_size, void* d_ws, size_t ws_size,
                              hipStream_t stream)
{
    const float* white   = (const float*)d_in[0];
    const float* black   = (const float*)d_in[1];
    const float* w_psqt  = (const float*)d_in[2];
    const float* w_acc   = (const float*)d_in[3];
    const float* b_acc   = (const float*)d_in[4];
    const float* w_layer = (const float*)d_in[5];
    float* out = (float*)d_out;

    const size_t bbytes = (size_t)TOTAL_CHUNKS * CHUNK_BYTES;  // 5,898,240
    unsigned short* Bp = (unsigned short*)d_ws;
    _Float16* partial = (_Float16*)((char*)d_ws + bbytes);

    const size_t per_ks = (size_t)8192 * NPAD * 2;             // 2.36 MB (f16)
    int KS = 1;
    const int cands[5] = {8, 5, 4, 2, 1};
    for (int i = 0; i < 5; ++i)
        if (bbytes + (size_t)cands[i] * per_ks <= ws_size) { KS = cands[i]; break; }
    int chunks_per_ks = TOTAL_CHUNKS / KS;

    prep_b   <<<dim3(2880),   dim3(256), 0, stream>>>(w_acc, w_psqt, Bp);
    gemm_main<<<dim3(32, KS), dim3(512), 0, stream>>>(white, black, Bp, partial, chunks_per_ks);
    epilogue <<<dim3(1024),   dim3(256), 0, stream>>>(partial, b_acc, w_layer, out, KS);
}